// Round 2
// baseline (9831.293 us; speedup 1.0000x reference)
//
#include <hip/hip_runtime.h>
#include <hip/hip_bf16.h>

// LSTM_Net round 2: persistent wavefront kernel.
//   prep:       fp32->bf16, xs transpose to [t][b][64], W0cat=[Wih0|Whh0] (K=832),
//               W1cat=[Wih1|Whh1] (K=1536), bias sums.
//   persistent: 192 WGs x 256thr. WG 0..95 = layer0 (8 h-cols each),
//               96..191 = layer1. Superstep s: layer0 computes t=s, layer1
//               computes t=s-1 (wavefront). Sync via per-WG monotone flags:
//               release-store own flag, relaxed-spin on all 192 + threadfence.
//               h double-buffered by superstep parity; c-state in registers.
//   head:       softsign MLP, unchanged.

#define B_  64
#define T_  256
#define IN_ 64
#define H_  768
#define G_  3072   // 4*H
#define K0_ 832    // IN_ + H_
#define K1_ 1536   // 2*H_
#define NWG0 96
#define NWG1 96
#define NWG  192

typedef __bf16 bf16_t;
typedef bf16_t bf16x8 __attribute__((ext_vector_type(8)));
typedef float  f32x4  __attribute__((ext_vector_type(4)));

__device__ __forceinline__ unsigned short f2bf(float f) {
    union { float f; unsigned u; } v; v.f = f;
    unsigned r = v.u + 0x7FFFu + ((v.u >> 16) & 1u);
    return (unsigned short)(r >> 16);
}
__device__ __forceinline__ float sigm(float x) {
    return 1.0f / (1.0f + expf(-x));
}
#define MFMA16(a, b, c) __builtin_amdgcn_mfma_f32_16x16x32_bf16((a), (b), (c), 0, 0, 0)

// ---------------- prep ----------------
__global__ __launch_bounds__(256) void prep_kernel(
    const float* __restrict__ x,
    const float* __restrict__ Wih0, const float* __restrict__ Whh0,
    const float* __restrict__ bih0, const float* __restrict__ bhh0,
    const float* __restrict__ Wih1, const float* __restrict__ Whh1,
    const float* __restrict__ bih1, const float* __restrict__ bhh1,
    unsigned short* __restrict__ xsT,    // [T][B][64]
    unsigned short* __restrict__ W0cat,  // [3072][832]
    unsigned short* __restrict__ W1cat,  // [3072][1536]
    float* __restrict__ bias0, float* __restrict__ bias1)
{
    int i = blockIdx.x * blockDim.x + threadIdx.x;
    int stride = gridDim.x * blockDim.x;
    // xsT[t][b][k] = x[b][t][k] / 1.5
    for (int j = i; j < B_ * T_ * IN_; j += stride) {
        int b = j >> 14;            // / (T_*IN_)
        int t = (j >> 6) & (T_ - 1);
        int k = j & (IN_ - 1);
        xsT[(((size_t)t * B_) + b) * IN_ + k] = f2bf(x[j] * (1.0f / 1.5f));
    }
    for (int j = i; j < G_ * IN_; j += stride) {
        int r = j >> 6; int k = j & 63;
        W0cat[(size_t)r * K0_ + k] = f2bf(Wih0[j]);
    }
    for (int j = i; j < G_ * H_; j += stride) {
        int r = j / H_; int k = j - r * H_;
        W0cat[(size_t)r * K0_ + IN_ + k] = f2bf(Whh0[j]);
        W1cat[(size_t)r * K1_ + k]       = f2bf(Wih1[j]);
        W1cat[(size_t)r * K1_ + H_ + k]  = f2bf(Whh1[j]);
    }
    for (int j = i; j < G_; j += stride) {
        bias0[j] = bih0[j] + bhh0[j];
        bias1[j] = bih1[j] + bhh1[j];
    }
}

// ---------------- persistent wavefront recurrence ----------------
// WG wg<96: layer0, h-cols [wg*8, wg*8+8). WG wg>=96: layer1, cols [(wg-96)*8 ..).
// Wave w = M-tile (batch rows w*16..w*16+15). Two 16-row mixed-gate B-tiles:
// tile0 rows = {gate i cols c0..c0+7, gate f ...}, tile1 = {g, o}.
// Flags: flags[wg] = number of completed supersteps (monotone). All WGs at
// superstep s wait until every flag >= s. Buffer parity: read h[s-1] from
// buf[(s+1)&1], write h[s] to buf[s&1] (layer1 shifted by 1: t=s-1).
__global__ __launch_bounds__(256) void lstm_persistent(
    const unsigned short* __restrict__ xsT,
    const unsigned short* __restrict__ W0cat,
    const unsigned short* __restrict__ W1cat,
    const float* __restrict__ bias0, const float* __restrict__ bias1,
    unsigned short* __restrict__ h1buf,   // [2][B][H] bf16 (layer0 output)
    unsigned short* __restrict__ h2buf,   // [2][B][H] bf16 (layer1 output)
    float* __restrict__ hf32,             // [B][H] fp32, written at t=T-1
    int* __restrict__ flags)              // [192]
{
    const int tid  = threadIdx.x;
    const int lane = tid & 63;
    const int wave = tid >> 6;
    const int wg   = blockIdx.x;
    const bool isL1 = (wg >= NWG0);
    const int c0 = (isL1 ? (wg - NWG0) : wg) * 8;
    const int frow = lane & 15;
    const int kof  = (lane >> 4) * 8;
    const int m0   = wave * 16;

    // B-tile row ids (gather rows of Wcat): oc = n*16+frow -> gate q=oc>>3, col=c0+(oc&7)
    const unsigned short* Wc = isL1 ? W1cat : W0cat;
    const int Kc = isL1 ? K1_ : K0_;
    int oc0 = frow,      q0 = oc0 >> 3, col0 = c0 + (oc0 & 7);
    int oc1 = 16 + frow, q1 = oc1 >> 3, col1 = c0 + (oc1 & 7);
    const unsigned short* Bp0 = Wc + (size_t)(q0 * H_ + col0) * Kc;
    const unsigned short* Bp1 = Wc + (size_t)(q1 * H_ + col1) * Kc;

    const float* bias = isL1 ? bias1 : bias0;
    const bool lowhalf = (lane & 15) < 8;
    const int ecol = c0 + (lane & 7);
    float bi = 0.f, bff = 0.f, bg = 0.f, bo = 0.f;
    if (lowhalf) {
        bi  = bias[0 * H_ + ecol];
        bff = bias[1 * H_ + ecol];
        bg  = bias[2 * H_ + ecol];
        bo  = bias[3 * H_ + ecol];
    }
    float creg[4] = {0.f, 0.f, 0.f, 0.f};

    for (int s = 0; s <= T_; ++s) {
        if (s > 0) {
            if (tid < NWG) {
                while (__hip_atomic_load(&flags[tid], __ATOMIC_RELAXED,
                                         __HIP_MEMORY_SCOPE_AGENT) < s)
                    __builtin_amdgcn_s_sleep(1);
            }
            __syncthreads();
            __threadfence();   // agent acquire: invalidate stale cached h
        }
        const bool active = isL1 ? (s >= 1) : (s < T_);
        if (active) {
            const int t = isL1 ? (s - 1) : s;
            f32x4 acc0 = {0.f, 0.f, 0.f, 0.f};
            f32x4 acc1 = {0.f, 0.f, 0.f, 0.f};
            if (!isL1) {
                // A = [xs_t (64) | h1_{t-1} (768)]
                const unsigned short* xsp =
                    xsT + ((size_t)t * B_ + m0 + frow) * IN_ + kof;
                const unsigned short* hr =
                    h1buf + (size_t)((s + 1) & 1) * B_ * H_ + (size_t)(m0 + frow) * H_ + kof;
                #pragma unroll
                for (int ki = 0; ki < 2; ki++) {
                    bf16x8 a  = *(const bf16x8*)(xsp + ki * 32);
                    bf16x8 b0 = *(const bf16x8*)(Bp0 + ki * 32 + kof);
                    bf16x8 b1 = *(const bf16x8*)(Bp1 + ki * 32 + kof);
                    acc0 = MFMA16(a, b0, acc0);
                    acc1 = MFMA16(a, b1, acc1);
                }
                #pragma unroll
                for (int ki = 2; ki < 26; ki++) {
                    bf16x8 a  = *(const bf16x8*)(hr + ki * 32 - 64);
                    bf16x8 b0 = *(const bf16x8*)(Bp0 + ki * 32 + kof);
                    bf16x8 b1 = *(const bf16x8*)(Bp1 + ki * 32 + kof);
                    acc0 = MFMA16(a, b0, acc0);
                    acc1 = MFMA16(a, b1, acc1);
                }
            } else {
                // A = [h1_t (768) | h2_{t-1} (768)]
                const unsigned short* h1r =
                    h1buf + (size_t)((s + 1) & 1) * B_ * H_ + (size_t)(m0 + frow) * H_ + kof;
                const unsigned short* h2r =
                    h2buf + (size_t)(s & 1) * B_ * H_ + (size_t)(m0 + frow) * H_ + kof;
                #pragma unroll
                for (int ki = 0; ki < 24; ki++) {
                    bf16x8 a  = *(const bf16x8*)(h1r + ki * 32);
                    bf16x8 b0 = *(const bf16x8*)(Bp0 + ki * 32 + kof);
                    bf16x8 b1 = *(const bf16x8*)(Bp1 + ki * 32 + kof);
                    acc0 = MFMA16(a, b0, acc0);
                    acc1 = MFMA16(a, b1, acc1);
                }
                #pragma unroll
                for (int ki = 24; ki < 48; ki++) {
                    bf16x8 a  = *(const bf16x8*)(h2r + (ki - 24) * 32);
                    bf16x8 b0 = *(const bf16x8*)(Bp0 + ki * 32 + kof);
                    bf16x8 b1 = *(const bf16x8*)(Bp1 + ki * 32 + kof);
                    acc0 = MFMA16(a, b0, acc0);
                    acc1 = MFMA16(a, b1, acc1);
                }
            }
            // Epilogue: lane (L&15)<8 holds gates i (acc0) and g (acc1) for col
            // ecol; partner lane^8 holds f and o for the same col.
            f32x4 pacc0, pacc1;
            #pragma unroll
            for (int j = 0; j < 4; j++) {
                pacc0[j] = __shfl_xor(acc0[j], 8);
                pacc1[j] = __shfl_xor(acc1[j], 8);
            }
            if (lowhalf) {
                unsigned short* hw = (!isL1)
                    ? h1buf + (size_t)(s & 1) * B_ * H_
                    : h2buf + (size_t)((s - 1) & 1) * B_ * H_;
                #pragma unroll
                for (int j = 0; j < 4; j++) {
                    int row = m0 + (lane >> 4) * 4 + j;
                    float pi = acc0[j]  + bi;
                    float pf = pacc0[j] + bff;
                    float pg = acc1[j]  + bg;
                    float po = pacc1[j] + bo;
                    float cn = sigm(pf) * creg[j] + sigm(pi) * tanhf(pg);
                    float hn = sigm(po) * tanhf(cn);
                    creg[j] = cn;
                    hw[(size_t)row * H_ + ecol] = f2bf(hn);
                    if (isL1 && t == T_ - 1) hf32[(size_t)row * H_ + ecol] = hn;
                }
            }
        }
        __syncthreads();                 // all waves' h stores complete (vmcnt drained)
        if (tid == 0) {
            __threadfence();             // agent release: push h to coherence point
            __hip_atomic_store(&flags[wg], s + 1, __ATOMIC_RELEASE,
                               __HIP_MEMORY_SCOPE_AGENT);
        }
    }
}

// ---------------- head ----------------
__global__ __launch_bounds__(256) void head_kernel(
    const float* __restrict__ hlast,
    const float* __restrict__ W1, const float* __restrict__ b1,
    const float* __restrict__ W2, const float* __restrict__ b2,
    float* __restrict__ out)
{
    __shared__ float hs[H_];
    __shared__ float partial[4];
    int b = blockIdx.x;
    int tid = threadIdx.x;
    for (int j = tid; j < H_; j += 256) hs[j] = hlast[(size_t)b * H_ + j];
    __syncthreads();
    float z = 0.f;
    const float* w = W1 + (size_t)tid * H_;
    for (int j = 0; j < H_; j++) z += hs[j] * w[j];
    z += b1[tid];
    z = z / (1.0f + fabsf(z));
    float p = z * W2[tid];
    #pragma unroll
    for (int off = 32; off > 0; off >>= 1) p += __shfl_down(p, off, 64);
    if ((tid & 63) == 0) partial[tid >> 6] = p;
    __syncthreads();
    if (tid == 0) {
        float s = partial[0] + partial[1] + partial[2] + partial[3];
        out[b] = (s + b2[0]) * 70.0f;
    }
}

extern "C" void kernel_launch(void* const* d_in, const int* in_sizes, int n_in,
                              void* d_out, int out_size, void* d_ws, size_t ws_size,
                              hipStream_t stream) {
    const float* x    = (const float*)d_in[0];
    const float* Wih0 = (const float*)d_in[1];
    const float* Whh0 = (const float*)d_in[2];
    const float* bih0 = (const float*)d_in[3];
    const float* bhh0 = (const float*)d_in[4];
    const float* Wih1 = (const float*)d_in[5];
    const float* Whh1 = (const float*)d_in[6];
    const float* bih1 = (const float*)d_in[7];
    const float* bhh1 = (const float*)d_in[8];
    const float* W1   = (const float*)d_in[9];
    const float* b1   = (const float*)d_in[10];
    const float* W2   = (const float*)d_in[11];
    const float* b2   = (const float*)d_in[12];
    float* out = (float*)d_out;

    // workspace layout (zero-region first: flags + h double-buffers)
    char* w = (char*)d_ws;
    int* flags = (int*)w;                         w += 1024;
    unsigned short* h1buf = (unsigned short*)w;   w += (size_t)2 * B_ * H_ * 2;
    unsigned short* h2buf = (unsigned short*)w;   w += (size_t)2 * B_ * H_ * 2;
    size_t zero_bytes = (size_t)(w - (char*)d_ws);
    unsigned short* xsT   = (unsigned short*)w;   w += (size_t)B_ * T_ * IN_ * 2;
    unsigned short* W0cat = (unsigned short*)w;   w += (size_t)G_ * K0_ * 2;
    unsigned short* W1cat = (unsigned short*)w;   w += (size_t)G_ * K1_ * 2;
    float* bias0 = (float*)w;                     w += G_ * 4;
    float* bias1 = (float*)w;                     w += G_ * 4;
    float* hf32  = (float*)w;                     w += (size_t)B_ * H_ * 4;

    hipMemsetAsync(d_ws, 0, zero_bytes, stream);
    prep_kernel<<<1024, 256, 0, stream>>>(x, Wih0, Whh0, bih0, bhh0,
                                          Wih1, Whh1, bih1, bhh1,
                                          xsT, W0cat, W1cat, bias0, bias1);
    lstm_persistent<<<NWG, 256, 0, stream>>>(xsT, W0cat, W1cat, bias0, bias1,
                                             h1buf, h2buf, hf32, flags);
    head_kernel<<<B_, 256, 0, stream>>>(hf32, W1, b1, W2, b2, out);
}

// Round 3
// 4231.028 us; speedup vs baseline: 2.3236x; 2.3236x over previous
//
#include <hip/hip_runtime.h>
#include <hip/hip_bf16.h>

// LSTM_Net round 3: persistent wavefront kernel, fence-free coherence.
//   - h state in RING buffers (one slot per timestep, never reused within a
//     launch) -> reader L2 lines are always first-touch -> plain cached loads
//     are coherent. No acquire fence / buffer_inv.
//   - h stores write-through to the coherence point via `global_store_short
//     ... sc1` (bypass L2, no dirty lines) -> no release fence / buffer_wbl2.
//   - flags: relaxed agent-scope atomics; store ordered after h stores by
//     __syncthreads()'s vmcnt(0) drain.
//   - layer0 waits only on layer0 flags (ring removes the WAR hazard that
//     coupled the two layers in round 2); layer1 waits on both.
// Round 2 failure mode this removes: 2x __threadfence() per WG per step =
// per-XCD L2 wbl2+inv storm (~38us/step, MfmaUtil 0.95%).

#define B_  64
#define T_  256
#define IN_ 64
#define H_  768
#define G_  3072   // 4*H
#define K0_ 832    // IN_ + H_
#define K1_ 1536   // 2*H_
#define NWG0 96
#define NWG  192
#define BH_ (B_ * H_)

typedef __bf16 bf16_t;
typedef bf16_t bf16x8 __attribute__((ext_vector_type(8)));
typedef float  f32x4  __attribute__((ext_vector_type(4)));

__device__ __forceinline__ unsigned short f2bf(float f) {
    union { float f; unsigned u; } v; v.f = f;
    unsigned r = v.u + 0x7FFFu + ((v.u >> 16) & 1u);
    return (unsigned short)(r >> 16);
}
__device__ __forceinline__ float sigm(float x) {
    return 1.0f / (1.0f + expf(-x));
}
// bf16 store that bypasses L1/L2 to the agent coherence point (MALL).
__device__ __forceinline__ void st_llc(unsigned short* p, unsigned short v) {
    asm volatile("global_store_short %0, %1, off sc1" :: "v"(p), "v"(v) : "memory");
}
#define MFMA16(a, b, c) __builtin_amdgcn_mfma_f32_16x16x32_bf16((a), (b), (c), 0, 0, 0)

// ---------------- prep ----------------
__global__ __launch_bounds__(256) void prep_kernel(
    const float* __restrict__ x,
    const float* __restrict__ Wih0, const float* __restrict__ Whh0,
    const float* __restrict__ bih0, const float* __restrict__ bhh0,
    const float* __restrict__ Wih1, const float* __restrict__ Whh1,
    const float* __restrict__ bih1, const float* __restrict__ bhh1,
    unsigned short* __restrict__ xsT,    // [T][B][64]
    unsigned short* __restrict__ W0cat,  // [3072][832]
    unsigned short* __restrict__ W1cat,  // [3072][1536]
    float* __restrict__ bias0, float* __restrict__ bias1,
    int* __restrict__ flags)             // [256]
{
    int i = blockIdx.x * blockDim.x + threadIdx.x;
    int stride = gridDim.x * blockDim.x;
    for (int j = i; j < B_ * T_ * IN_; j += stride) {
        int b = j >> 14;
        int t = (j >> 6) & (T_ - 1);
        int k = j & (IN_ - 1);
        xsT[(((size_t)t * B_) + b) * IN_ + k] = f2bf(x[j] * (1.0f / 1.5f));
    }
    for (int j = i; j < G_ * IN_; j += stride) {
        int r = j >> 6; int k = j & 63;
        W0cat[(size_t)r * K0_ + k] = f2bf(Wih0[j]);
    }
    for (int j = i; j < G_ * H_; j += stride) {
        int r = j / H_; int k = j - r * H_;
        W0cat[(size_t)r * K0_ + IN_ + k] = f2bf(Whh0[j]);
        W1cat[(size_t)r * K1_ + k]       = f2bf(Wih1[j]);
        W1cat[(size_t)r * K1_ + H_ + k]  = f2bf(Whh1[j]);
    }
    for (int j = i; j < G_; j += stride) {
        bias0[j] = bih0[j] + bhh0[j];
        bias1[j] = bih1[j] + bhh1[j];
    }
    // flags: layer0 (0..95) start at 0; layer1 (96..191) start at 1 so the
    // layer1 self-wait at superstep 1 (which reads no h2) passes immediately.
    for (int j = i; j < 256; j += stride) flags[j] = (j >= NWG0) ? 1 : 0;
}

// ---------------- persistent wavefront recurrence ----------------
__global__ __launch_bounds__(256) void lstm_persistent(
    const unsigned short* __restrict__ xsT,
    const unsigned short* __restrict__ W0cat,
    const unsigned short* __restrict__ W1cat,
    const float* __restrict__ bias0, const float* __restrict__ bias1,
    unsigned short* __restrict__ h1ring,  // [T][B][H] bf16
    unsigned short* __restrict__ h2ring,  // [T][B][H] bf16
    float* __restrict__ hf32,             // [B][H] fp32 (t = T-1)
    int* __restrict__ flags)              // [256]
{
    const int tid  = threadIdx.x;
    const int lane = tid & 63;
    const int wave = tid >> 6;
    const int wg   = blockIdx.x;
    const bool isL1 = (wg >= NWG0);
    const int c0 = (isL1 ? (wg - NWG0) : wg) * 8;
    const int frow = lane & 15;
    const int kof  = (lane >> 4) * 8;
    const int m0   = wave * 16;

    const unsigned short* Wc = isL1 ? W1cat : W0cat;
    const int Kc = isL1 ? K1_ : K0_;
    int q0 = frow >> 3,       col0 = c0 + (frow & 7);        // B-tile0: gates i,f
    int q1 = (16 + frow) >> 3, col1 = c0 + (frow & 7);       // B-tile1: gates g,o
    const unsigned short* Bp0 = Wc + (size_t)(q0 * H_ + col0) * Kc;
    const unsigned short* Bp1 = Wc + (size_t)(q1 * H_ + col1) * Kc;

    const float* bias = isL1 ? bias1 : bias0;
    const bool lowhalf = (lane & 15) < 8;
    const int ecol = c0 + (lane & 7);
    float bi = 0.f, bff = 0.f, bg = 0.f, bo = 0.f;
    if (lowhalf) {
        bi  = bias[0 * H_ + ecol];
        bff = bias[1 * H_ + ecol];
        bg  = bias[2 * H_ + ecol];
        bo  = bias[3 * H_ + ecol];
    }
    float creg[4] = {0.f, 0.f, 0.f, 0.f};
    const size_t rowoff = (size_t)(m0 + frow) * H_ + kof;

    if (!isL1) {
        // ---------------- layer 0: supersteps 0..T-1, computes t = s --------
        for (int s = 0; s < T_; ++s) {
            if (s > 0) {
                if (tid < NWG0) {
                    while (__hip_atomic_load(&flags[tid], __ATOMIC_RELAXED,
                                             __HIP_MEMORY_SCOPE_AGENT) < s)
                        __builtin_amdgcn_s_sleep(1);
                }
                __syncthreads();
            }
            f32x4 acc0 = {0.f, 0.f, 0.f, 0.f};
            f32x4 acc1 = {0.f, 0.f, 0.f, 0.f};
            const unsigned short* xsp =
                xsT + ((size_t)s * B_ + m0 + frow) * IN_ + kof;
            #pragma unroll
            for (int ki = 0; ki < 2; ki++) {
                bf16x8 a  = *(const bf16x8*)(xsp + ki * 32);
                bf16x8 b0 = *(const bf16x8*)(Bp0 + ki * 32 + kof);
                bf16x8 b1 = *(const bf16x8*)(Bp1 + ki * 32 + kof);
                acc0 = MFMA16(a, b0, acc0);
                acc1 = MFMA16(a, b1, acc1);
            }
            if (s > 0) {
                const unsigned short* hr = h1ring + (size_t)(s - 1) * BH_ + rowoff;
                #pragma unroll
                for (int kj = 0; kj < 24; kj++) {
                    bf16x8 a  = *(const bf16x8*)(hr + kj * 32);
                    bf16x8 b0 = *(const bf16x8*)(Bp0 + (kj + 2) * 32 + kof);
                    bf16x8 b1 = *(const bf16x8*)(Bp1 + (kj + 2) * 32 + kof);
                    acc0 = MFMA16(a, b0, acc0);
                    acc1 = MFMA16(a, b1, acc1);
                }
            }
            f32x4 pacc0, pacc1;
            #pragma unroll
            for (int j = 0; j < 4; j++) {
                pacc0[j] = __shfl_xor(acc0[j], 8);
                pacc1[j] = __shfl_xor(acc1[j], 8);
            }
            if (lowhalf) {
                unsigned short* hw = h1ring + (size_t)s * BH_;
                #pragma unroll
                for (int j = 0; j < 4; j++) {
                    int row = m0 + (lane >> 4) * 4 + j;
                    float pi = acc0[j]  + bi;
                    float pf = pacc0[j] + bff;
                    float pg = acc1[j]  + bg;
                    float po = pacc1[j] + bo;
                    float cn = sigm(pf) * creg[j] + sigm(pi) * tanhf(pg);
                    float hn = sigm(po) * tanhf(cn);
                    creg[j] = cn;
                    st_llc(hw + (size_t)row * H_ + ecol, f2bf(hn));
                }
            }
            __syncthreads();   // drains vmcnt(0): sc1 h-stores are at MALL
            if (tid == 0)
                __hip_atomic_store(&flags[wg], s + 1, __ATOMIC_RELAXED,
                                   __HIP_MEMORY_SCOPE_AGENT);
        }
    } else {
        // ---------------- layer 1: supersteps 1..T, computes t = s-1 --------
        for (int s = 1; s <= T_; ++s) {
            if (tid < NWG) {
                while (__hip_atomic_load(&flags[tid], __ATOMIC_RELAXED,
                                         __HIP_MEMORY_SCOPE_AGENT) < s)
                    __builtin_amdgcn_s_sleep(1);
            }
            __syncthreads();
            const int t = s - 1;
            f32x4 acc0 = {0.f, 0.f, 0.f, 0.f};
            f32x4 acc1 = {0.f, 0.f, 0.f, 0.f};
            const unsigned short* h1r = h1ring + (size_t)t * BH_ + rowoff;
            #pragma unroll
            for (int ki = 0; ki < 24; ki++) {
                bf16x8 a  = *(const bf16x8*)(h1r + ki * 32);
                bf16x8 b0 = *(const bf16x8*)(Bp0 + ki * 32 + kof);
                bf16x8 b1 = *(const bf16x8*)(Bp1 + ki * 32 + kof);
                acc0 = MFMA16(a, b0, acc0);
                acc1 = MFMA16(a, b1, acc1);
            }
            if (t > 0) {
                const unsigned short* h2r = h2ring + (size_t)(t - 1) * BH_ + rowoff;
                #pragma unroll
                for (int ki = 24; ki < 48; ki++) {
                    bf16x8 a  = *(const bf16x8*)(h2r + (ki - 24) * 32);
                    bf16x8 b0 = *(const bf16x8*)(Bp0 + ki * 32 + kof);
                    bf16x8 b1 = *(const bf16x8*)(Bp1 + ki * 32 + kof);
                    acc0 = MFMA16(a, b0, acc0);
                    acc1 = MFMA16(a, b1, acc1);
                }
            }
            f32x4 pacc0, pacc1;
            #pragma unroll
            for (int j = 0; j < 4; j++) {
                pacc0[j] = __shfl_xor(acc0[j], 8);
                pacc1[j] = __shfl_xor(acc1[j], 8);
            }
            if (lowhalf) {
                unsigned short* hw = h2ring + (size_t)t * BH_;
                #pragma unroll
                for (int j = 0; j < 4; j++) {
                    int row = m0 + (lane >> 4) * 4 + j;
                    float pi = acc0[j]  + bi;
                    float pf = pacc0[j] + bff;
                    float pg = acc1[j]  + bg;
                    float po = pacc1[j] + bo;
                    float cn = sigm(pf) * creg[j] + sigm(pi) * tanhf(pg);
                    float hn = sigm(po) * tanhf(cn);
                    creg[j] = cn;
                    st_llc(hw + (size_t)row * H_ + ecol, f2bf(hn));
                    if (t == T_ - 1) hf32[(size_t)row * H_ + ecol] = hn;
                }
            }
            __syncthreads();
            if (tid == 0)
                __hip_atomic_store(&flags[NWG0 + (wg - NWG0)], s + 1,
                                   __ATOMIC_RELAXED, __HIP_MEMORY_SCOPE_AGENT);
        }
    }
}

// ---------------- head ----------------
__global__ __launch_bounds__(256) void head_kernel(
    const float* __restrict__ hlast,
    const float* __restrict__ W1, const float* __restrict__ b1,
    const float* __restrict__ W2, const float* __restrict__ b2,
    float* __restrict__ out)
{
    __shared__ float hs[H_];
    __shared__ float partial[4];
    int b = blockIdx.x;
    int tid = threadIdx.x;
    for (int j = tid; j < H_; j += 256) hs[j] = hlast[(size_t)b * H_ + j];
    __syncthreads();
    float z = 0.f;
    const float* w = W1 + (size_t)tid * H_;
    for (int j = 0; j < H_; j++) z += hs[j] * w[j];
    z += b1[tid];
    z = z / (1.0f + fabsf(z));
    float p = z * W2[tid];
    #pragma unroll
    for (int off = 32; off > 0; off >>= 1) p += __shfl_down(p, off, 64);
    if ((tid & 63) == 0) partial[tid >> 6] = p;
    __syncthreads();
    if (tid == 0) {
        float s = partial[0] + partial[1] + partial[2] + partial[3];
        out[b] = (s + b2[0]) * 70.0f;
    }
}

extern "C" void kernel_launch(void* const* d_in, const int* in_sizes, int n_in,
                              void* d_out, int out_size, void* d_ws, size_t ws_size,
                              hipStream_t stream) {
    const float* x    = (const float*)d_in[0];
    const float* Wih0 = (const float*)d_in[1];
    const float* Whh0 = (const float*)d_in[2];
    const float* bih0 = (const float*)d_in[3];
    const float* bhh0 = (const float*)d_in[4];
    const float* Wih1 = (const float*)d_in[5];
    const float* Whh1 = (const float*)d_in[6];
    const float* bih1 = (const float*)d_in[7];
    const float* bhh1 = (const float*)d_in[8];
    const float* W1   = (const float*)d_in[9];
    const float* b1   = (const float*)d_in[10];
    const float* W2   = (const float*)d_in[11];
    const float* b2   = (const float*)d_in[12];
    float* out = (float*)d_out;

    char* w = (char*)d_ws;
    int* flags = (int*)w;                         w += 1024;
    unsigned short* h1ring = (unsigned short*)w;  w += (size_t)T_ * BH_ * 2;  // 25.2 MB
    unsigned short* h2ring = (unsigned short*)w;  w += (size_t)T_ * BH_ * 2;  // 25.2 MB
    unsigned short* xsT    = (unsigned short*)w;  w += (size_t)B_ * T_ * IN_ * 2;
    unsigned short* W0cat  = (unsigned short*)w;  w += (size_t)G_ * K0_ * 2;
    unsigned short* W1cat  = (unsigned short*)w;  w += (size_t)G_ * K1_ * 2;
    float* bias0 = (float*)w;                     w += G_ * 4;
    float* bias1 = (float*)w;                     w += G_ * 4;
    float* hf32  = (float*)w;                     w += (size_t)B_ * H_ * 4;

    prep_kernel<<<1024, 256, 0, stream>>>(x, Wih0, Whh0, bih0, bhh0,
                                          Wih1, Whh1, bih1, bhh1,
                                          xsT, W0cat, W1cat, bias0, bias1, flags);
    lstm_persistent<<<NWG, 256, 0, stream>>>(xsT, W0cat, W1cat, bias0, bias1,
                                             h1ring, h2ring, hf32, flags);
    head_kernel<<<B_, 256, 0, stream>>>(hf32, W1, b1, W2, b2, out);
}

// Round 4
// 3783.391 us; speedup vs baseline: 2.5985x; 1.1183x over previous
//
#include <hip/hip_runtime.h>
#include <hip/hip_bf16.h>

// LSTM_Net round 4: persistent wavefront kernel, coalesced MALL traffic.
// Delta vs round 3 (16.2us/superstep, MfmaUtil 2.3%):
//   - h rings re-laid out as [t][cb][row][8] (cb = 8-col block owned by one
//     WG). WG output per step = contiguous 1KB; stored as ONE coalesced
//     global_store_dword sc1 per wave (vs 512 scattered 2B write-throughs
//     per WG -> MALL partial-line RMW storm, the round-3 bottleneck).
//     Reads stay coalesced: 16B/lane contiguous per quad.
//   - Epilogue patch assembled in LDS (wave-internal DS ordering, no extra
//     barrier).
//   - Layer0 computes the xs-contribution MFMAs BEFORE the flag spin
//     (independent of h -> hides detect latency).
// Coherence model unchanged from r3: ring = first-touch reads (plain cached
// loads safe), sc1 write-through stores (no dirty L2), relaxed agent-scope
// flags ordered by __syncthreads vmcnt drain. No fences anywhere.

#define B_  64
#define T_  256
#define IN_ 64
#define H_  768
#define G_  3072   // 4*H
#define K0_ 832    // IN_ + H_
#define K1_ 1536   // 2*H_
#define NWG0 96
#define NWG  192
#define CB_  96            // col blocks per layer (H/8)
#define SLOT_ (CB_ * 64 * 8)   // elements per ring slot = 49152

typedef __bf16 bf16_t;
typedef bf16_t bf16x8 __attribute__((ext_vector_type(8)));
typedef float  f32x4  __attribute__((ext_vector_type(4)));

__device__ __forceinline__ unsigned short f2bf(float f) {
    union { float f; unsigned u; } v; v.f = f;
    unsigned r = v.u + 0x7FFFu + ((v.u >> 16) & 1u);
    return (unsigned short)(r >> 16);
}
__device__ __forceinline__ float sigm(float x) {
    return 1.0f / (1.0f + expf(-x));
}
// dword store that bypasses L1/L2 to the agent coherence point (MALL).
__device__ __forceinline__ void st_llc_u32(unsigned* p, unsigned v) {
    asm volatile("global_store_dword %0, %1, off sc1" :: "v"(p), "v"(v) : "memory");
}
#define MFMA16(a, b, c) __builtin_amdgcn_mfma_f32_16x16x32_bf16((a), (b), (c), 0, 0, 0)

// ---------------- prep ----------------
__global__ __launch_bounds__(256) void prep_kernel(
    const float* __restrict__ x,
    const float* __restrict__ Wih0, const float* __restrict__ Whh0,
    const float* __restrict__ bih0, const float* __restrict__ bhh0,
    const float* __restrict__ Wih1, const float* __restrict__ Whh1,
    const float* __restrict__ bih1, const float* __restrict__ bhh1,
    unsigned short* __restrict__ xsT,    // [T][B][64]
    unsigned short* __restrict__ W0cat,  // [3072][832]
    unsigned short* __restrict__ W1cat,  // [3072][1536]
    float* __restrict__ bias0, float* __restrict__ bias1,
    int* __restrict__ flags)             // [256]
{
    int i = blockIdx.x * blockDim.x + threadIdx.x;
    int stride = gridDim.x * blockDim.x;
    for (int j = i; j < B_ * T_ * IN_; j += stride) {
        int b = j >> 14;
        int t = (j >> 6) & (T_ - 1);
        int k = j & (IN_ - 1);
        xsT[(((size_t)t * B_) + b) * IN_ + k] = f2bf(x[j] * (1.0f / 1.5f));
    }
    for (int j = i; j < G_ * IN_; j += stride) {
        int r = j >> 6; int k = j & 63;
        W0cat[(size_t)r * K0_ + k] = f2bf(Wih0[j]);
    }
    for (int j = i; j < G_ * H_; j += stride) {
        int r = j / H_; int k = j - r * H_;
        W0cat[(size_t)r * K0_ + IN_ + k] = f2bf(Whh0[j]);
        W1cat[(size_t)r * K1_ + k]       = f2bf(Wih1[j]);
        W1cat[(size_t)r * K1_ + H_ + k]  = f2bf(Whh1[j]);
    }
    for (int j = i; j < G_; j += stride) {
        bias0[j] = bih0[j] + bhh0[j];
        bias1[j] = bih1[j] + bhh1[j];
    }
    for (int j = i; j < 256; j += stride) flags[j] = (j >= NWG0) ? 1 : 0;
}

// ---------------- persistent wavefront recurrence ----------------
// h rings: [t][cb][row][8] bf16; cb = col-block (8 cols), one per WG.
__global__ __launch_bounds__(256) void lstm_persistent(
    const unsigned short* __restrict__ xsT,
    const unsigned short* __restrict__ W0cat,
    const unsigned short* __restrict__ W1cat,
    const float* __restrict__ bias0, const float* __restrict__ bias1,
    unsigned short* __restrict__ h1ring,  // [T][96][64][8]
    unsigned short* __restrict__ h2ring,  // [T][96][64][8]
    float* __restrict__ hf32,             // [B][H] fp32 (t = T-1)
    int* __restrict__ flags)              // [256]
{
    __shared__ unsigned short ldsb[4][16][8];   // per-wave 16x8 output patch

    const int tid  = threadIdx.x;
    const int lane = tid & 63;
    const int wave = tid >> 6;
    const int wg   = blockIdx.x;
    const bool isL1 = (wg >= NWG0);
    const int cb   = isL1 ? (wg - NWG0) : wg;
    const int c0   = cb * 8;
    const int frow = lane & 15;
    const int q    = lane >> 4;       // quad id 0..3
    const int kof  = q * 8;
    const int m0   = wave * 16;

    const unsigned short* Wc = isL1 ? W1cat : W0cat;
    const int Kc = isL1 ? K1_ : K0_;
    int q0 = frow >> 3,        col0 = c0 + (frow & 7);   // B-tile0: gates i,f
    int q1 = 2 + (frow >> 3),  col1 = c0 + (frow & 7);   // B-tile1: gates g,o
    const unsigned short* Bp0 = Wc + (size_t)(q0 * H_ + col0) * Kc + kof;
    const unsigned short* Bp1 = Wc + (size_t)(q1 * H_ + col1) * Kc + kof;

    const float* bias = isL1 ? bias1 : bias0;
    const bool lowhalf = (lane & 15) < 8;
    const int ecol = c0 + (lane & 7);
    float bi = 0.f, bff = 0.f, bg = 0.f, bo = 0.f;
    if (lowhalf) {
        bi  = bias[0 * H_ + ecol];
        bff = bias[1 * H_ + ecol];
        bg  = bias[2 * H_ + ecol];
        bo  = bias[3 * H_ + ecol];
    }
    float creg[4] = {0.f, 0.f, 0.f, 0.f};

    // A-operand offset within a ring slot: quad q reads cb-index (kj*4+q),
    // row m0+frow, 8 contiguous cols.
    const size_t aoff = (size_t)q * 512 + (size_t)(m0 + frow) * 8;
    // Store: wave writes 256B at slot + cb*512 (+ wave's row range).
    // Lane dword: row = m0 + (lane>>2), colpair = lane&3.
    const size_t stoff_e = (size_t)cb * 512 + (size_t)(m0 + (lane >> 2)) * 8
                         + (size_t)(lane & 3) * 2;   // elements

    if (!isL1) {
        // ------------- layer 0: superstep s computes t = s ------------------
        for (int s = 0; s < T_; ++s) {
            // xs contribution first: independent of flags/h.
            f32x4 acc0 = {0.f, 0.f, 0.f, 0.f};
            f32x4 acc1 = {0.f, 0.f, 0.f, 0.f};
            {
                const unsigned short* xsp =
                    xsT + ((size_t)s * B_ + m0 + frow) * IN_ + kof;
                #pragma unroll
                for (int ki = 0; ki < 2; ki++) {
                    bf16x8 a  = *(const bf16x8*)(xsp + ki * 32);
                    bf16x8 b0 = *(const bf16x8*)(Bp0 + ki * 32);
                    bf16x8 b1 = *(const bf16x8*)(Bp1 + ki * 32);
                    acc0 = MFMA16(a, b0, acc0);
                    acc1 = MFMA16(a, b1, acc1);
                }
            }
            if (s > 0) {
                if (tid < NWG0) {
                    while (__hip_atomic_load(&flags[tid], __ATOMIC_RELAXED,
                                             __HIP_MEMORY_SCOPE_AGENT) < s)
                        __builtin_amdgcn_s_sleep(1);
                }
                __syncthreads();
                const unsigned short* hr = h1ring + (size_t)(s - 1) * SLOT_ + aoff;
                #pragma unroll
                for (int kj = 0; kj < 24; kj++) {
                    bf16x8 a  = *(const bf16x8*)(hr + kj * 2048);
                    bf16x8 b0 = *(const bf16x8*)(Bp0 + (kj + 2) * 32);
                    bf16x8 b1 = *(const bf16x8*)(Bp1 + (kj + 2) * 32);
                    acc0 = MFMA16(a, b0, acc0);
                    acc1 = MFMA16(a, b1, acc1);
                }
            }
            f32x4 pacc0, pacc1;
            #pragma unroll
            for (int j = 0; j < 4; j++) {
                pacc0[j] = __shfl_xor(acc0[j], 8);
                pacc1[j] = __shfl_xor(acc1[j], 8);
            }
            if (lowhalf) {
                #pragma unroll
                for (int j = 0; j < 4; j++) {
                    float pi = acc0[j]  + bi;
                    float pf = pacc0[j] + bff;
                    float pg = acc1[j]  + bg;
                    float po = pacc1[j] + bo;
                    float cn = sigm(pf) * creg[j] + sigm(pi) * tanhf(pg);
                    float hn = sigm(po) * tanhf(cn);
                    creg[j] = cn;
                    ldsb[wave][q * 4 + j][lane & 7] = f2bf(hn);
                }
            }
            // wave-internal DS ordering: reads below see this wave's writes.
            unsigned v = ((const unsigned*)&ldsb[wave][0][0])[lane];
            st_llc_u32((unsigned*)(h1ring + (size_t)s * SLOT_ + stoff_e), v);
            __syncthreads();   // drains vmcnt(0): store is at MALL
            if (tid == 0)
                __hip_atomic_store(&flags[wg], s + 1, __ATOMIC_RELAXED,
                                   __HIP_MEMORY_SCOPE_AGENT);
        }
    } else {
        // ------------- layer 1: superstep s computes t = s - 1 --------------
        for (int s = 1; s <= T_; ++s) {
            if (tid < NWG) {
                while (__hip_atomic_load(&flags[tid], __ATOMIC_RELAXED,
                                         __HIP_MEMORY_SCOPE_AGENT) < s)
                    __builtin_amdgcn_s_sleep(1);
            }
            __syncthreads();
            const int t = s - 1;
            f32x4 acc0 = {0.f, 0.f, 0.f, 0.f};
            f32x4 acc1 = {0.f, 0.f, 0.f, 0.f};
            const unsigned short* h1r = h1ring + (size_t)t * SLOT_ + aoff;
            #pragma unroll
            for (int ki = 0; ki < 24; ki++) {
                bf16x8 a  = *(const bf16x8*)(h1r + ki * 2048);
                bf16x8 b0 = *(const bf16x8*)(Bp0 + ki * 32);
                bf16x8 b1 = *(const bf16x8*)(Bp1 + ki * 32);
                acc0 = MFMA16(a, b0, acc0);
                acc1 = MFMA16(a, b1, acc1);
            }
            if (t > 0) {
                const unsigned short* h2r = h2ring + (size_t)(t - 1) * SLOT_ + aoff;
                #pragma unroll
                for (int ki = 0; ki < 24; ki++) {
                    bf16x8 a  = *(const bf16x8*)(h2r + ki * 2048);
                    bf16x8 b0 = *(const bf16x8*)(Bp0 + (ki + 24) * 32);
                    bf16x8 b1 = *(const bf16x8*)(Bp1 + (ki + 24) * 32);
                    acc0 = MFMA16(a, b0, acc0);
                    acc1 = MFMA16(a, b1, acc1);
                }
            }
            f32x4 pacc0, pacc1;
            #pragma unroll
            for (int j = 0; j < 4; j++) {
                pacc0[j] = __shfl_xor(acc0[j], 8);
                pacc1[j] = __shfl_xor(acc1[j], 8);
            }
            if (lowhalf) {
                #pragma unroll
                for (int j = 0; j < 4; j++) {
                    int row = m0 + q * 4 + j;   // q in {0,1}: rows m0..m0+7
                    float pi = acc0[j]  + bi;
                    float pf = pacc0[j] + bff;
                    float pg = acc1[j]  + bg;
                    float po = pacc1[j] + bo;
                    float cn = sigm(pf) * creg[j] + sigm(pi) * tanhf(pg);
                    float hn = sigm(po) * tanhf(cn);
                    creg[j] = cn;
                    ldsb[wave][q * 4 + j][lane & 7] = f2bf(hn);
                    if (t == T_ - 1) hf32[(size_t)row * H_ + ecol] = hn;
                }
            }
            unsigned v = ((const unsigned*)&ldsb[wave][0][0])[lane];
            st_llc_u32((unsigned*)(h2ring + (size_t)t * SLOT_ + stoff_e), v);
            __syncthreads();
            if (tid == 0)
                __hip_atomic_store(&flags[wg], s + 1, __ATOMIC_RELAXED,
                                   __HIP_MEMORY_SCOPE_AGENT);
        }
    }
}

// ---------------- head ----------------
__global__ __launch_bounds__(256) void head_kernel(
    const float* __restrict__ hlast,
    const float* __restrict__ W1, const float* __restrict__ b1,
    const float* __restrict__ W2, const float* __restrict__ b2,
    float* __restrict__ out)
{
    __shared__ float hs[H_];
    __shared__ float partial[4];
    int b = blockIdx.x;
    int tid = threadIdx.x;
    for (int j = tid; j < H_; j += 256) hs[j] = hlast[(size_t)b * H_ + j];
    __syncthreads();
    float z = 0.f;
    const float* w = W1 + (size_t)tid * H_;
    for (int j = 0; j < H_; j++) z += hs[j] * w[j];
    z += b1[tid];
    z = z / (1.0f + fabsf(z));
    float p = z * W2[tid];
    #pragma unroll
    for (int off = 32; off > 0; off >>= 1) p += __shfl_down(p, off, 64);
    if ((tid & 63) == 0) partial[tid >> 6] = p;
    __syncthreads();
    if (tid == 0) {
        float s = partial[0] + partial[1] + partial[2] + partial[3];
        out[b] = (s + b2[0]) * 70.0f;
    }
}

extern "C" void kernel_launch(void* const* d_in, const int* in_sizes, int n_in,
                              void* d_out, int out_size, void* d_ws, size_t ws_size,
                              hipStream_t stream) {
    const float* x    = (const float*)d_in[0];
    const float* Wih0 = (const float*)d_in[1];
    const float* Whh0 = (const float*)d_in[2];
    const float* bih0 = (const float*)d_in[3];
    const float* bhh0 = (const float*)d_in[4];
    const float* Wih1 = (const float*)d_in[5];
    const float* Whh1 = (const float*)d_in[6];
    const float* bih1 = (const float*)d_in[7];
    const float* bhh1 = (const float*)d_in[8];
    const float* W1   = (const float*)d_in[9];
    const float* b1   = (const float*)d_in[10];
    const float* W2   = (const float*)d_in[11];
    const float* b2   = (const float*)d_in[12];
    float* out = (float*)d_out;

    char* w = (char*)d_ws;
    int* flags = (int*)w;                         w += 1024;
    unsigned short* h1ring = (unsigned short*)w;  w += (size_t)T_ * SLOT_ * 2;
    unsigned short* h2ring = (unsigned short*)w;  w += (size_t)T_ * SLOT_ * 2;
    unsigned short* xsT    = (unsigned short*)w;  w += (size_t)B_ * T_ * IN_ * 2;
    unsigned short* W0cat  = (unsigned short*)w;  w += (size_t)G_ * K0_ * 2;
    unsigned short* W1cat  = (unsigned short*)w;  w += (size_t)G_ * K1_ * 2;
    float* bias0 = (float*)w;                     w += G_ * 4;
    float* bias1 = (float*)w;                     w += G_ * 4;
    float* hf32  = (float*)w;                     w += (size_t)B_ * H_ * 4;

    prep_kernel<<<1024, 256, 0, stream>>>(x, Wih0, Whh0, bih0, bhh0,
                                          Wih1, Whh1, bih1, bhh1,
                                          xsT, W0cat, W1cat, bias0, bias1, flags);
    lstm_persistent<<<NWG, 256, 0, stream>>>(xsT, W0cat, W1cat, bias0, bias1,
                                             h1ring, h2ring, hf32, flags);
    head_kernel<<<B_, 256, 0, stream>>>(hf32, W1, b1, W2, b2, out);
}

// Round 5
// 3657.644 us; speedup vs baseline: 2.6879x; 1.0344x over previous
//
#include <hip/hip_runtime.h>
#include <hip/hip_bf16.h>

// LSTM_Net round 5: persistent wavefront kernel, aggregated-counter sync.
// Delta vs round 4 (14.4us/superstep, MfmaUtil 2.6%):
//   - Round-4 flag scheme = 192 threads/WG spinning agent-scope loads on a
//     12-line flag array -> ~37k chip-wide pollers congesting the MALL
//     (detect latency ~10us/step). Replaced by TWO epoch counters (one per
//     layer, 1KB apart): producers fire-and-forget atomicAdd after the
//     post-store barrier; ONE poller thread per counter per WG (tid 0 ->
//     ctr0, tid 64 -> ctr1, separate waves). ~100x less poll traffic.
//   - Thresholds: L0 step s waits ctr0 >= 96*s; L1 step s waits
//     ctr0 >= 96*s && ctr1 >= 96*(s-1). Monotone, no reset, no WAR (rings).
// Unchanged from r4: [t][cb][row][8] ring layout, coalesced sc1 write-through
// h stores (WRITE_SIZE halved in r4, confirming the store path), LDS epilogue
// assembly, xs-MFMAs before the wait, no fences.

#define B_  64
#define T_  256
#define IN_ 64
#define H_  768
#define G_  3072   // 4*H
#define K0_ 832    // IN_ + H_
#define K1_ 1536   // 2*H_
#define NWG0 96
#define NWG  192
#define CB_  96            // col blocks per layer (H/8)
#define SLOT_ (CB_ * 64 * 8)   // elements per ring slot = 49152

typedef __bf16 bf16_t;
typedef bf16_t bf16x8 __attribute__((ext_vector_type(8)));
typedef float  f32x4  __attribute__((ext_vector_type(4)));

__device__ __forceinline__ unsigned short f2bf(float f) {
    union { float f; unsigned u; } v; v.f = f;
    unsigned r = v.u + 0x7FFFu + ((v.u >> 16) & 1u);
    return (unsigned short)(r >> 16);
}
__device__ __forceinline__ float sigm(float x) {
    return 1.0f / (1.0f + expf(-x));
}
// dword store that bypasses L1/L2 to the agent coherence point (MALL).
__device__ __forceinline__ void st_llc_u32(unsigned* p, unsigned v) {
    asm volatile("global_store_dword %0, %1, off sc1" :: "v"(p), "v"(v) : "memory");
}
#define MFMA16(a, b, c) __builtin_amdgcn_mfma_f32_16x16x32_bf16((a), (b), (c), 0, 0, 0)

// ---------------- prep ----------------
__global__ __launch_bounds__(256) void prep_kernel(
    const float* __restrict__ x,
    const float* __restrict__ Wih0, const float* __restrict__ Whh0,
    const float* __restrict__ bih0, const float* __restrict__ bhh0,
    const float* __restrict__ Wih1, const float* __restrict__ Whh1,
    const float* __restrict__ bih1, const float* __restrict__ bhh1,
    unsigned short* __restrict__ xsT,    // [T][B][64]
    unsigned short* __restrict__ W0cat,  // [3072][832]
    unsigned short* __restrict__ W1cat,  // [3072][1536]
    float* __restrict__ bias0, float* __restrict__ bias1,
    int* __restrict__ ctrs)              // [512] (ctr0 at 0, ctr1 at 256)
{
    int i = blockIdx.x * blockDim.x + threadIdx.x;
    int stride = gridDim.x * blockDim.x;
    for (int j = i; j < B_ * T_ * IN_; j += stride) {
        int b = j >> 14;
        int t = (j >> 6) & (T_ - 1);
        int k = j & (IN_ - 1);
        xsT[(((size_t)t * B_) + b) * IN_ + k] = f2bf(x[j] * (1.0f / 1.5f));
    }
    for (int j = i; j < G_ * IN_; j += stride) {
        int r = j >> 6; int k = j & 63;
        W0cat[(size_t)r * K0_ + k] = f2bf(Wih0[j]);
    }
    for (int j = i; j < G_ * H_; j += stride) {
        int r = j / H_; int k = j - r * H_;
        W0cat[(size_t)r * K0_ + IN_ + k] = f2bf(Whh0[j]);
        W1cat[(size_t)r * K1_ + k]       = f2bf(Wih1[j]);
        W1cat[(size_t)r * K1_ + H_ + k]  = f2bf(Whh1[j]);
    }
    for (int j = i; j < G_; j += stride) {
        bias0[j] = bih0[j] + bhh0[j];
        bias1[j] = bih1[j] + bhh1[j];
    }
    for (int j = i; j < 512; j += stride) ctrs[j] = 0;
}

// ---------------- persistent wavefront recurrence ----------------
// h rings: [t][cb][row][8] bf16; cb = col-block (8 cols), one per WG.
__global__ __launch_bounds__(256) void lstm_persistent(
    const unsigned short* __restrict__ xsT,
    const unsigned short* __restrict__ W0cat,
    const unsigned short* __restrict__ W1cat,
    const float* __restrict__ bias0, const float* __restrict__ bias1,
    unsigned short* __restrict__ h1ring,  // [T][96][64][8]
    unsigned short* __restrict__ h2ring,  // [T][96][64][8]
    float* __restrict__ hf32,             // [B][H] fp32 (t = T-1)
    int* __restrict__ ctrs)               // ctr0 = ctrs[0], ctr1 = ctrs[256]
{
    __shared__ unsigned short ldsb[4][16][8];   // per-wave 16x8 output patch

    const int tid  = threadIdx.x;
    const int lane = tid & 63;
    const int wave = tid >> 6;
    const int wg   = blockIdx.x;
    const bool isL1 = (wg >= NWG0);
    const int cb   = isL1 ? (wg - NWG0) : wg;
    const int c0   = cb * 8;
    const int frow = lane & 15;
    const int q    = lane >> 4;       // quad id 0..3
    const int kof  = q * 8;
    const int m0   = wave * 16;

    int* ctr0 = &ctrs[0];
    int* ctr1 = &ctrs[256];

    const unsigned short* Wc = isL1 ? W1cat : W0cat;
    const int Kc = isL1 ? K1_ : K0_;
    int q0 = frow >> 3,        col0 = c0 + (frow & 7);   // B-tile0: gates i,f
    int q1 = 2 + (frow >> 3),  col1 = c0 + (frow & 7);   // B-tile1: gates g,o
    const unsigned short* Bp0 = Wc + (size_t)(q0 * H_ + col0) * Kc + kof;
    const unsigned short* Bp1 = Wc + (size_t)(q1 * H_ + col1) * Kc + kof;

    const float* bias = isL1 ? bias1 : bias0;
    const bool lowhalf = (lane & 15) < 8;
    const int ecol = c0 + (lane & 7);
    float bi = 0.f, bff = 0.f, bg = 0.f, bo = 0.f;
    if (lowhalf) {
        bi  = bias[0 * H_ + ecol];
        bff = bias[1 * H_ + ecol];
        bg  = bias[2 * H_ + ecol];
        bo  = bias[3 * H_ + ecol];
    }
    float creg[4] = {0.f, 0.f, 0.f, 0.f};

    // A-operand offset within a ring slot: quad q reads cb-index (kj*4+q),
    // row m0+frow, 8 contiguous cols.
    const size_t aoff = (size_t)q * 512 + (size_t)(m0 + frow) * 8;
    // Store: wave writes 256B at slot + cb*512 (+ wave's row range).
    const size_t stoff_e = (size_t)cb * 512 + (size_t)(m0 + (lane >> 2)) * 8
                         + (size_t)(lane & 3) * 2;   // elements

    if (!isL1) {
        // ------------- layer 0: superstep s computes t = s ------------------
        for (int s = 0; s < T_; ++s) {
            // xs contribution first: independent of sync/h.
            f32x4 acc0 = {0.f, 0.f, 0.f, 0.f};
            f32x4 acc1 = {0.f, 0.f, 0.f, 0.f};
            {
                const unsigned short* xsp =
                    xsT + ((size_t)s * B_ + m0 + frow) * IN_ + kof;
                #pragma unroll
                for (int ki = 0; ki < 2; ki++) {
                    bf16x8 a  = *(const bf16x8*)(xsp + ki * 32);
                    bf16x8 b0 = *(const bf16x8*)(Bp0 + ki * 32);
                    bf16x8 b1 = *(const bf16x8*)(Bp1 + ki * 32);
                    acc0 = MFMA16(a, b0, acc0);
                    acc1 = MFMA16(a, b1, acc1);
                }
            }
            if (s > 0) {
                if (tid == 0) {
                    while (__hip_atomic_load(ctr0, __ATOMIC_RELAXED,
                                             __HIP_MEMORY_SCOPE_AGENT) < NWG0 * s)
                        __builtin_amdgcn_s_sleep(1);
                }
                __syncthreads();
                const unsigned short* hr = h1ring + (size_t)(s - 1) * SLOT_ + aoff;
                #pragma unroll
                for (int kj = 0; kj < 24; kj++) {
                    bf16x8 a  = *(const bf16x8*)(hr + kj * 2048);
                    bf16x8 b0 = *(const bf16x8*)(Bp0 + (kj + 2) * 32);
                    bf16x8 b1 = *(const bf16x8*)(Bp1 + (kj + 2) * 32);
                    acc0 = MFMA16(a, b0, acc0);
                    acc1 = MFMA16(a, b1, acc1);
                }
            }
            f32x4 pacc0, pacc1;
            #pragma unroll
            for (int j = 0; j < 4; j++) {
                pacc0[j] = __shfl_xor(acc0[j], 8);
                pacc1[j] = __shfl_xor(acc1[j], 8);
            }
            if (lowhalf) {
                #pragma unroll
                for (int j = 0; j < 4; j++) {
                    float pi = acc0[j]  + bi;
                    float pf = pacc0[j] + bff;
                    float pg = acc1[j]  + bg;
                    float po = pacc1[j] + bo;
                    float cn = sigm(pf) * creg[j] + sigm(pi) * tanhf(pg);
                    float hn = sigm(po) * tanhf(cn);
                    creg[j] = cn;
                    ldsb[wave][q * 4 + j][lane & 7] = f2bf(hn);
                }
            }
            // wave-internal DS ordering: read below sees this wave's writes.
            unsigned v = ((const unsigned*)&ldsb[wave][0][0])[lane];
            st_llc_u32((unsigned*)(h1ring + (size_t)s * SLOT_ + stoff_e), v);
            __syncthreads();   // drains vmcnt(0): stores are at MALL
            if (tid == 0) atomicAdd(ctr0, 1);   // fire-and-forget, device scope
        }
    } else {
        // ------------- layer 1: superstep s computes t = s - 1 --------------
        for (int s = 1; s <= T_; ++s) {
            const int t = s - 1;
            if (tid == 0) {
                while (__hip_atomic_load(ctr0, __ATOMIC_RELAXED,
                                         __HIP_MEMORY_SCOPE_AGENT) < NWG0 * s)
                    __builtin_amdgcn_s_sleep(1);
            }
            if (tid == 64 && t > 0) {
                while (__hip_atomic_load(ctr1, __ATOMIC_RELAXED,
                                         __HIP_MEMORY_SCOPE_AGENT) < NWG0 * (s - 1))
                    __builtin_amdgcn_s_sleep(1);
            }
            __syncthreads();
            f32x4 acc0 = {0.f, 0.f, 0.f, 0.f};
            f32x4 acc1 = {0.f, 0.f, 0.f, 0.f};
            const unsigned short* h1r = h1ring + (size_t)t * SLOT_ + aoff;
            #pragma unroll
            for (int ki = 0; ki < 24; ki++) {
                bf16x8 a  = *(const bf16x8*)(h1r + ki * 2048);
                bf16x8 b0 = *(const bf16x8*)(Bp0 + ki * 32);
                bf16x8 b1 = *(const bf16x8*)(Bp1 + ki * 32);
                acc0 = MFMA16(a, b0, acc0);
                acc1 = MFMA16(a, b1, acc1);
            }
            if (t > 0) {
                const unsigned short* h2r = h2ring + (size_t)(t - 1) * SLOT_ + aoff;
                #pragma unroll
                for (int ki = 0; ki < 24; ki++) {
                    bf16x8 a  = *(const bf16x8*)(h2r + ki * 2048);
                    bf16x8 b0 = *(const bf16x8*)(Bp0 + (ki + 24) * 32);
                    bf16x8 b1 = *(const bf16x8*)(Bp1 + (ki + 24) * 32);
                    acc0 = MFMA16(a, b0, acc0);
                    acc1 = MFMA16(a, b1, acc1);
                }
            }
            f32x4 pacc0, pacc1;
            #pragma unroll
            for (int j = 0; j < 4; j++) {
                pacc0[j] = __shfl_xor(acc0[j], 8);
                pacc1[j] = __shfl_xor(acc1[j], 8);
            }
            if (lowhalf) {
                #pragma unroll
                for (int j = 0; j < 4; j++) {
                    int row = m0 + q * 4 + j;
                    float pi = acc0[j]  + bi;
                    float pf = pacc0[j] + bff;
                    float pg = acc1[j]  + bg;
                    float po = pacc1[j] + bo;
                    float cn = sigm(pf) * creg[j] + sigm(pi) * tanhf(pg);
                    float hn = sigm(po) * tanhf(cn);
                    creg[j] = cn;
                    ldsb[wave][q * 4 + j][lane & 7] = f2bf(hn);
                    if (t == T_ - 1) hf32[(size_t)row * H_ + ecol] = hn;
                }
            }
            unsigned v = ((const unsigned*)&ldsb[wave][0][0])[lane];
            st_llc_u32((unsigned*)(h2ring + (size_t)t * SLOT_ + stoff_e), v);
            __syncthreads();
            if (tid == 0) atomicAdd(ctr1, 1);
        }
    }
}

// ---------------- head ----------------
__global__ __launch_bounds__(256) void head_kernel(
    const float* __restrict__ hlast,
    const float* __restrict__ W1, const float* __restrict__ b1,
    const float* __restrict__ W2, const float* __restrict__ b2,
    float* __restrict__ out)
{
    __shared__ float hs[H_];
    __shared__ float partial[4];
    int b = blockIdx.x;
    int tid = threadIdx.x;
    for (int j = tid; j < H_; j += 256) hs[j] = hlast[(size_t)b * H_ + j];
    __syncthreads();
    float z = 0.f;
    const float* w = W1 + (size_t)tid * H_;
    for (int j = 0; j < H_; j++) z += hs[j] * w[j];
    z += b1[tid];
    z = z / (1.0f + fabsf(z));
    float p = z * W2[tid];
    #pragma unroll
    for (int off = 32; off > 0; off >>= 1) p += __shfl_down(p, off, 64);
    if ((tid & 63) == 0) partial[tid >> 6] = p;
    __syncthreads();
    if (tid == 0) {
        float s = partial[0] + partial[1] + partial[2] + partial[3];
        out[b] = (s + b2[0]) * 70.0f;
    }
}

extern "C" void kernel_launch(void* const* d_in, const int* in_sizes, int n_in,
                              void* d_out, int out_size, void* d_ws, size_t ws_size,
                              hipStream_t stream) {
    const float* x    = (const float*)d_in[0];
    const float* Wih0 = (const float*)d_in[1];
    const float* Whh0 = (const float*)d_in[2];
    const float* bih0 = (const float*)d_in[3];
    const float* bhh0 = (const float*)d_in[4];
    const float* Wih1 = (const float*)d_in[5];
    const float* Whh1 = (const float*)d_in[6];
    const float* bih1 = (const float*)d_in[7];
    const float* bhh1 = (const float*)d_in[8];
    const float* W1   = (const float*)d_in[9];
    const float* b1   = (const float*)d_in[10];
    const float* W2   = (const float*)d_in[11];
    const float* b2   = (const float*)d_in[12];
    float* out = (float*)d_out;

    char* w = (char*)d_ws;
    int* ctrs = (int*)w;                          w += 2048;
    unsigned short* h1ring = (unsigned short*)w;  w += (size_t)T_ * SLOT_ * 2;
    unsigned short* h2ring = (unsigned short*)w;  w += (size_t)T_ * SLOT_ * 2;
    unsigned short* xsT    = (unsigned short*)w;  w += (size_t)B_ * T_ * IN_ * 2;
    unsigned short* W0cat  = (unsigned short*)w;  w += (size_t)G_ * K0_ * 2;
    unsigned short* W1cat  = (unsigned short*)w;  w += (size_t)G_ * K1_ * 2;
    float* bias0 = (float*)w;                     w += G_ * 4;
    float* bias1 = (float*)w;                     w += G_ * 4;
    float* hf32  = (float*)w;                     w += (size_t)B_ * H_ * 4;

    prep_kernel<<<1024, 256, 0, stream>>>(x, Wih0, Whh0, bih0, bhh0,
                                          Wih1, Whh1, bih1, bhh1,
                                          xsT, W0cat, W1cat, bias0, bias1, ctrs);
    lstm_persistent<<<NWG, 256, 0, stream>>>(xsT, W0cat, W1cat, bias0, bias1,
                                             h1ring, h2ring, hf32, ctrs);
    head_kernel<<<B_, 256, 0, stream>>>(hf32, W1, b1, W2, b2, out);
}